// Round 13
// baseline (1220.258 us; speedup 1.0000x reference)
//
#include <hip/hip_runtime.h>
#include <hip/hip_bf16.h>
#include <math.h>

// ---------------------------------------------------------------------------
// SwinDiT block, f32 I/O + bf16 MFMA internals, MI355X.
// B=1, D=16,H=64,W=64 -> L=65536 tokens, C=512. Windows 4x8x8=256 tokens,
// 256 windows, 8 heads, d=64. HIDDEN=2048.
// ---------------------------------------------------------------------------

typedef __attribute__((ext_vector_type(8))) short short8;   // 8 x bf16
typedef __attribute__((ext_vector_type(4))) short bs4;      // 4 x bf16
typedef __attribute__((ext_vector_type(4))) float f32x4;

typedef const __attribute__((address_space(1))) unsigned int gu32;
typedef __attribute__((address_space(3))) unsigned int lu32;

__device__ __forceinline__ float bf2f(short s) {
  unsigned int u = ((unsigned int)(unsigned short)s) << 16;
  float f;
  __builtin_memcpy(&f, &u, 4);
  return f;
}
__device__ __forceinline__ short f2bf(float f) {
  unsigned int u;
  __builtin_memcpy(&u, &f, 4);
  u += 0x7FFFu + ((u >> 16) & 1u);   // RNE
  return (short)(u >> 16);
}
__device__ __forceinline__ short f2bf_trunc(float f) {
  unsigned int u;
  __builtin_memcpy(&u, &f, 4);
  return (short)(u >> 16);
}

// window-layout row p -> original token index s (roll(-2,-4,-4) + window partition)
__device__ __forceinline__ int win_to_src(int p) {
  int wi = p >> 8, t = p & 255;
  int sd = (((wi >> 6) << 2) + (t >> 6) + 2) & 15;
  int sh = ((((wi >> 3) & 7) << 3) + ((t >> 3) & 7) + 4) & 63;
  int sw = (((wi & 7) << 3) + (t & 7) + 4) & 63;
  return (sd << 12) | (sh << 6) | sw;
}

// ---------------------------------------------------------------------------
// K0: mod = silu(t_emb) @ ada_w + ada_b   -> f32 [3072]
// ---------------------------------------------------------------------------
__global__ __launch_bounds__(256) void mod_kernel(
    const float* __restrict__ t_emb, const float* __restrict__ ada_w,
    const float* __restrict__ ada_b, float* __restrict__ mod) {
  __shared__ float sl[512];
  int tid = threadIdx.x;
  for (int r = 0; r < 2; ++r) {
    float x = t_emb[r * 256 + tid];
    sl[r * 256 + tid] = x / (1.f + expf(-x));
  }
  __syncthreads();
  int col = blockIdx.x * 256 + tid;
  float acc = ada_b[col];
  for (int k = 0; k < 512; ++k)
    acc += sl[k] * ada_w[(size_t)k * 3072 + col];
  mod[col] = acc;
}

// ---------------------------------------------------------------------------
// K1: rel-pos bias expand, TRANSPOSED bf16: biasT[head][key j][q i]
// ---------------------------------------------------------------------------
__global__ __launch_bounds__(256) void bias_kernel(
    const float* __restrict__ rel_table, short* __restrict__ biasT) {
  int head = blockIdx.x >> 8;
  int j = blockIdx.x & 255;   // key
  int i = threadIdx.x;        // q
  int di = i >> 6, hi = (i >> 3) & 7, wi = i & 7;
  int dj = j >> 6, hj = (j >> 3) & 7, wj = j & 7;
  int idx = (di - dj + 3) * 225 + (hi - hj + 7) * 15 + (wi - wj + 7);
  biasT[(size_t)blockIdx.x * 256 + i] = f2bf(rel_table[idx * 8 + head]);
}

// ---------------------------------------------------------------------------
// K2: PERMUTED transpose (all GEMM weights): in f32 [K][Nin] -> out bf16
// [Nin][K], out row j holds logical w column Lcol(j) = (j&~63) + 4*(j&15)
// + ((j>>4)&3).  GEMM frag (n,l15) then maps to 4 CONTIGUOUS logical cols.
// grid (Nin/64, K/64), 256 threads.
// ---------------------------------------------------------------------------
__global__ __launch_bounds__(256) void perm_transpose_kernel(
    const float* __restrict__ in, short* __restrict__ out, int Nin, int K) {
  __shared__ float t[64][65];
  int a = blockIdx.x;          // n-block
  int kb = blockIdx.y;         // k-block
  int tx = threadIdx.x & 63, ty = threadIdx.x >> 6;
#pragma unroll
  for (int r = 0; r < 16; ++r) {
    int kk = ty * 16 + r;
    t[kk][tx] = in[(size_t)(kb * 64 + kk) * Nin + a * 64 + tx];
  }
  __syncthreads();
#pragma unroll
  for (int r = 0; r < 16; ++r) {
    int jl = ty * 16 + r;                       // local out row
    int lc = 4 * (jl & 15) + ((jl >> 4) & 3);   // Lcol local
    out[(size_t)(a * 64 + jl) * K + kb * 64 + tx] = f2bf(t[tx][lc]);
  }
}

// ---------------------------------------------------------------------------
// K3: LayerNorm + adaLN modulate. f32 in -> bf16 out.
// GATHER=1: out row p <- src row win_to_src(p)
// ---------------------------------------------------------------------------
template <int GATHER>
__global__ __launch_bounds__(256) void ln_kernel(
    const float* __restrict__ xin, short* __restrict__ xout,
    const float* __restrict__ shv, const float* __restrict__ scv) {
  int wave = threadIdx.x >> 6, lane = threadIdx.x & 63;
  int p = blockIdx.x * 4 + wave;
  int s = GATHER ? win_to_src(p) : p;
  const f32x4* px = (const f32x4*)(xin + (size_t)s * 512 + lane * 8);
  f32x4 a = px[0], b = px[1];
  float xs[8];
#pragma unroll
  for (int j = 0; j < 4; ++j) { xs[j] = a[j]; xs[4 + j] = b[j]; }
  float sum = 0.f, sq = 0.f;
#pragma unroll
  for (int j = 0; j < 8; ++j) { sum += xs[j]; sq += xs[j] * xs[j]; }
#pragma unroll
  for (int off = 1; off < 64; off <<= 1) {
    sum += __shfl_xor(sum, off, 64);
    sq += __shfl_xor(sq, off, 64);
  }
  float mean = sum * (1.f / 512.f);
  float var = sq * (1.f / 512.f) - mean * mean;
  float rs = rsqrtf(var + 1e-5f);
  short8 o;
#pragma unroll
  for (int j = 0; j < 8; ++j) {
    int c = lane * 8 + j;
    float val = (xs[j] - mean) * rs * (1.f + scv[c]) + shv[c];
    o[j] = f2bf(val);
  }
  *(short8*)(xout + (size_t)p * 512 + lane * 8) = o;
}

// ---------------------------------------------------------------------------
// K4: STREAMING GEMM  C[M,N] = A @ BT^T + bias.  Weights-stationary:
// block = 512 rows x 64 cols; B-strip (64 x 512K = 64 KB, sigma-swizzled,
// sigma: byte ^= ((byte>>10)&7)<<4 within 1024-B rows) staged in LDS ONCE;
// each of 8 waves owns 64 rows and free-runs K with ZERO barriers:
// A-frags global->register (16 rows x 64 B per b128 = 1 KB/instr, L2-
// resident panel via bn-innermost + XCD chunking), B from LDS (~2-way
// banks), 256 MFMA/wave. fc2 (K=2048) loops KCH=4 B-chunks.
// 2 blocks/CU (LDS 64 KB). Vectorized epilogues (64-col strip = one
// permutation group; lane covers logical cols colb..colb+3).
// EPI: 0 = qkv: (acc+bias)*0.125 on q cols -> bs4 store
//      1 = fc1: bias + tanh-GELU -> bs4 store
//      2 = proj: scatter window-row -> token-row; f32x4 resid+gate store
//      3 = fc2:  f32x4 resid+gate store (Cf = d_out)
// ---------------------------------------------------------------------------
template <int EPI, int KCH>
__global__ __launch_bounds__(512) void gemm_stream_kernel(
    const short* __restrict__ A, const short* __restrict__ BT,
    const float* __restrict__ bias, void* __restrict__ Cv,
    int M, int N, int K, int nbn,
    const float* __restrict__ resid, const float* __restrict__ gate) {
  __shared__ __align__(16) short Bs[64 * 512];   // 64 KB

  int nwg = gridDim.x;
  int bid = blockIdx.x;
  int q = nwg >> 3, r = nwg & 7;
  int xcd = bid & 7, idx = bid >> 3;
  int swz = (xcd < r ? xcd * (q + 1) : r * (q + 1) + (xcd - r) * q) + idx;
  int bm = swz / nbn, bn = swz % nbn;

  int tid = threadIdx.x;
  int lane = tid & 63, wave = tid >> 6;          // wave 0..7 -> M rows
  int l15 = lane & 15, lg = lane >> 4;

  const size_t rowb = (size_t)K * 2;   // bytes per row (A and BT)

  // B staging addresses: dest byte o (linear), src = sigma(o) within strip
  const char* gB[8];
  int loB[8];
#pragma unroll
  for (int rr = 0; rr < 8; ++rr) {
    int o = rr * 8192 + tid * 16;
    int so = o ^ (((o >> 10) & 7) << 4);   // involution sigma (1024-B rows)
    loB[rr] = o;
    gB[rr] = (const char*)BT + (size_t)(bn * 64 + (so >> 10)) * rowb + (so & 1023);
  }

  // A per-m row base pointers (include lg segment)
  const char* pA[4];
#pragma unroll
  for (int m = 0; m < 4; ++m)
    pA[m] = (const char*)A + (size_t)(bm * 512 + wave * 64 + m * 16 + l15) * rowb + lg * 16;

  f32x4 acc[4][4];
#pragma unroll
  for (int m = 0; m < 4; ++m)
#pragma unroll
    for (int n = 0; n < 4; ++n) acc[m][n] = (f32x4){0.f, 0.f, 0.f, 0.f};

  const int swr = (l15 & 7) << 4;

  for (int kc = 0; kc < KCH; ++kc) {
    if (kc) __syncthreads();               // all waves done reading prev chunk
#pragma unroll
    for (int rr = 0; rr < 8; ++rr)
      __builtin_amdgcn_global_load_lds((gu32*)(gB[rr] + kc * 1024),
                                       (lu32*)((char*)Bs + loB[rr]), 16, 0, 0);
    __syncthreads();                       // vmcnt(0) + barrier: strip ready

    // barrier-free K streaming: 16 ks steps x (4 A-glb + 4 B-ds + 16 MFMA)
#pragma unroll 4
    for (int ks = 0; ks < 16; ++ks) {
      short8 af[4], bfr[4];
#pragma unroll
      for (int m = 0; m < 4; ++m)
        af[m] = *(const short8*)(pA[m] + kc * 1024 + ks * 64);
#pragma unroll
      for (int n = 0; n < 4; ++n)
        bfr[n] = *(const short8*)((const char*)Bs + (n * 16 + l15) * 1024 +
                                  ((ks * 64 + lg * 16) ^ swr));
#pragma unroll
      for (int m = 0; m < 4; ++m)
#pragma unroll
        for (int n = 0; n < 4; ++n)
          acc[m][n] = __builtin_amdgcn_mfma_f32_16x16x32_bf16(af[m], bfr[n], acc[m][n], 0, 0, 0);
    }
  }

  // vectorized epilogues: lane covers logical cols colb..colb+3
  int colb = bn * 64 + 4 * l15;
  f32x4 bv4 = *(const f32x4*)(bias + colb);
  if (EPI == 0) {
    float sc = (colb < 512) ? 0.125f : 1.f;   // q-scale (exact pow2)
#pragma unroll
    for (int m = 0; m < 4; ++m)
#pragma unroll
      for (int i = 0; i < 4; ++i) {
        int row = bm * 512 + wave * 64 + m * 16 + lg * 4 + i;
        bs4 pk;
#pragma unroll
        for (int n = 0; n < 4; ++n) pk[n] = f2bf_trunc((acc[m][n][i] + bv4[n]) * sc);
        *(bs4*)((short*)Cv + (size_t)row * N + colb) = pk;
      }
  } else if (EPI == 1) {
#pragma unroll
    for (int m = 0; m < 4; ++m)
#pragma unroll
      for (int i = 0; i < 4; ++i) {
        int row = bm * 512 + wave * 64 + m * 16 + lg * 4 + i;
        bs4 pk;
#pragma unroll
        for (int n = 0; n < 4; ++n) {
          float v = acc[m][n][i] + bv4[n];
          float tt = v * (0.7978845608f + 0.0356774081f * v * v);
          float sg = 1.f / (1.f + __expf(-2.f * tt));
          pk[n] = f2bf_trunc(v * sg);
        }
        *(bs4*)((short*)Cv + (size_t)row * N + colb) = pk;
      }
  } else {
    f32x4 gv = *(const f32x4*)(gate + colb);
#pragma unroll
    for (int m = 0; m < 4; ++m)
#pragma unroll
      for (int i = 0; i < 4; ++i) {
        int row = bm * 512 + wave * 64 + m * 16 + lg * 4 + i;
        int s = (EPI == 2) ? win_to_src(row) : row;
        f32x4 rv = *(const f32x4*)(resid + (size_t)s * 512 + colb);
        f32x4 o;
#pragma unroll
        for (int n = 0; n < 4; ++n) o[n] = rv[n] + gv[n] * (acc[m][n][i] + bv4[n]);
        *(f32x4*)((float*)Cv + (size_t)s * 512 + colb) = o;
      }
  }
}

// ---------------------------------------------------------------------------
// K5: window attention, one block per (window, head), 8 waves x 32 q-rows
// (512 thr). Max-free softmax (bounded logits), per-lane partial sums,
// one deferred reduce. LDS 54272 B -> 2 blocks/CU = 16 waves/CU.
// ---------------------------------------------------------------------------
__global__ __launch_bounds__(512) void attn_kernel(
    const short* __restrict__ qkv, const short* __restrict__ biasT,
    short* __restrict__ aout) {
  __shared__ __align__(16) short vt[64][264];      // V^T: [d][key]   33792 B
  __shared__ __align__(16) short pl[8][32][40];    // per-wave P slice 20480 B
  int win = blockIdx.x, head = blockIdx.y;
  int tid = threadIdx.x, lane = tid & 63, wave = tid >> 6;   // wave 0..7
  int l15 = lane & 15, lg = lane >> 4;
  const short* qp = qkv + (size_t)win * 256 * 1536 + head * 64;
  const short* kp = qp + 512;
  const short* vp = qp + 1024;

  // stage V transposed: 512 threads, thread pair splits d-halves of one key
  int key = tid >> 1, dh = (tid & 1) * 32;
#pragma unroll
  for (int r = 0; r < 4; ++r) {
    short8 vv = *(const short8*)(vp + (size_t)key * 1536 + dh + r * 8);
#pragma unroll
    for (int j = 0; j < 8; ++j) vt[dh + r * 8 + j][key] = vv[j];
  }

  // Q fragments (q pre-scaled by 0.125 in qkv epilogue); wave owns 32 rows
  short8 qf[2][2];
#pragma unroll
  for (int m = 0; m < 2; ++m)
#pragma unroll
    for (int kk = 0; kk < 2; ++kk)
      qf[m][kk] = *(const short8*)(qp + (size_t)(wave * 32 + m * 16 + l15) * 1536 + kk * 32 + lg * 8);

  __syncthreads();

  float lsum[2][4];
  f32x4 ao[2][4];
#pragma unroll
  for (int m = 0; m < 2; ++m)
#pragma unroll
    for (int i = 0; i < 4; ++i) lsum[m][i] = 0.f;
#pragma unroll
  for (int m = 0; m < 2; ++m)
#pragma unroll
    for (int n = 0; n < 4; ++n) ao[m][n] = (f32x4){0.f, 0.f, 0.f, 0.f};

  for (int kc = 0; kc < 4; ++kc) {
    f32x4 sv[2][4];
#pragma unroll
    for (int m = 0; m < 2; ++m)
#pragma unroll
      for (int n = 0; n < 4; ++n) sv[m][n] = (f32x4){0.f, 0.f, 0.f, 0.f};
#pragma unroll
    for (int n = 0; n < 4; ++n)
#pragma unroll
      for (int kk = 0; kk < 2; ++kk) {
        short8 kf = *(const short8*)(kp + (size_t)(kc * 64 + n * 16 + l15) * 1536 + kk * 32 + lg * 8);
#pragma unroll
        for (int m = 0; m < 2; ++m)
          sv[m][n] = __builtin_amdgcn_mfma_f32_16x16x32_bf16(qf[m][kk], kf, sv[m][n], 0, 0, 0);
      }
    // + rel-pos bias, P = exp(S), per-lane partial sums
#pragma unroll
    for (int n = 0; n < 4; ++n) {
      const short* bq = biasT + (size_t)(head * 256 + kc * 64 + n * 16 + l15) * 256 + wave * 32 + lg * 4;
#pragma unroll
      for (int m = 0; m < 2; ++m) {
        bs4 bt = *(const bs4*)(bq + m * 16);
#pragma unroll
        for (int i = 0; i < 4; ++i) {
          float pe = __expf(sv[m][n][i] + bf2f(bt[i]));
          sv[m][n][i] = pe;
          lsum[m][i] += pe;
        }
      }
    }
    // P slices of 32 keys: store -> read A-frag -> PV MFMA
#pragma unroll
    for (int s = 0; s < 2; ++s) {
#pragma unroll
      for (int m = 0; m < 2; ++m)
#pragma unroll
        for (int nn = 0; nn < 2; ++nn) {
          int n = 2 * s + nn;
#pragma unroll
          for (int i = 0; i < 4; ++i)
            pl[wave][m * 16 + lg * 4 + i][nn * 16 + l15] = f2bf_trunc(sv[m][n][i]);
        }
      short8 pf[2];
#pragma unroll
      for (int m = 0; m < 2; ++m)
        pf[m] = *(const short8*)&pl[wave][m * 16 + l15][lg * 8];
#pragma unroll
      for (int n2 = 0; n2 < 4; ++n2) {
        short8 vf = *(const short8*)&vt[n2 * 16 + l15][kc * 64 + s * 32 + lg * 8];
#pragma unroll
        for (int m = 0; m < 2; ++m)
          ao[m][n2] = __builtin_amdgcn_mfma_f32_16x16x32_bf16(pf[m], vf, ao[m][n2], 0, 0, 0);
      }
    }
  }

  // deferred cross-lane sum reduce (within the 16 col-lanes, lg preserved)
#pragma unroll
  for (int m = 0; m < 2; ++m)
#pragma unroll
    for (int i = 0; i < 4; ++i) {
#pragma unroll
      for (int off = 1; off < 16; off <<= 1)
        lsum[m][i] += __shfl_xor(lsum[m][i], off, 64);
    }

  // normalize + store [win-layout token][head*64+d]
#pragma unroll
  for (int m = 0; m < 2; ++m)
#pragma unroll
    for (int i = 0; i < 4; ++i) {
      float inv = 1.f / lsum[m][i];
      int row = win * 256 + wave * 32 + m * 16 + lg * 4 + i;
#pragma unroll
      for (int n = 0; n < 4; ++n)
        aout[(size_t)row * 512 + head * 64 + n * 16 + l15] = f2bf(ao[m][n][i] * inv);
    }
}

// ---------------------------------------------------------------------------
// launch
// ---------------------------------------------------------------------------
extern "C" void kernel_launch(void* const* d_in, const int* in_sizes, int n_in,
                              void* d_out, int out_size, void* d_ws, size_t ws_size,
                              hipStream_t stream) {
  (void)in_sizes; (void)n_in; (void)out_size; (void)ws_size;
  const float* x         = (const float*)d_in[0];
  const float* t_emb     = (const float*)d_in[1];
  const float* ada_w     = (const float*)d_in[2];
  const float* ada_b     = (const float*)d_in[3];
  const float* rel_table = (const float*)d_in[4];
  const float* qkv_w     = (const float*)d_in[5];
  const float* qkv_b     = (const float*)d_in[6];
  const float* proj_w    = (const float*)d_in[7];
  const float* proj_b    = (const float*)d_in[8];
  const float* fc1_w     = (const float*)d_in[9];
  const float* fc1_b     = (const float*)d_in[10];
  const float* fc2_w     = (const float*)d_in[11];
  const float* fc2_b     = (const float*)d_in[12];
  float* out = (float*)d_out;
  char* ws = (char*)d_ws;

  // workspace layout (bytes); total ~327 MB
  float* mod    = (float*)(ws);                    // 3072 f32 (16 KB reserved)
  short* biasT  = (short*)(ws + 16384);            // 8*256*256 bf16 = 1 MB
  short* qkvwT  = (short*)(ws + 16384 + 2097152);  // 1536*512 bf16 (perm)
  short* projwT = qkvwT + 1536 * 512;              // 512*512 (perm)
  short* fc1wT  = projwT + 512 * 512;              // 2048*512 (perm)
  short* fc2wT  = fc1wT + 2048 * 512;              // 512*2048 (perm)
  short* xn     = (short*)(ws + 8404992);          // 65536*512 bf16
  short* qkvb   = xn + (size_t)65536 * 512;        // 65536*1536 bf16
  short* attno  = qkvb + (size_t)65536 * 1536;     // 65536*512 bf16
  short* h1     = qkvb;                            // alias: 65536*2048 over qkvb+attno
  float* x2     = out;                             // MSA residual output lives in d_out

  mod_kernel<<<12, 256, 0, stream>>>(t_emb, ada_w, ada_b, mod);
  bias_kernel<<<2048, 256, 0, stream>>>(rel_table, biasT);
  perm_transpose_kernel<<<dim3(24, 8), 256, 0, stream>>>(qkv_w, qkvwT, 1536, 512);
  perm_transpose_kernel<<<dim3(8, 8), 256, 0, stream>>>(proj_w, projwT, 512, 512);
  perm_transpose_kernel<<<dim3(32, 8), 256, 0, stream>>>(fc1_w, fc1wT, 2048, 512);
  perm_transpose_kernel<<<dim3(8, 32), 256, 0, stream>>>(fc2_w, fc2wT, 512, 2048);

  // MSA: gather+LN+modulate -> xn (window layout, bf16)
  ln_kernel<1><<<16384, 256, 0, stream>>>(x, xn, mod + 0, mod + 512);
  // qkv = xn @ qkv_w + b  (bf16, q pre-scaled); 512-row x 64-col blocks
  gemm_stream_kernel<0, 1><<<128 * 24, 512, 0, stream>>>(
      xn, qkvwT, qkv_b, qkvb, 65536, 1536, 512, 24, nullptr, nullptr);
  attn_kernel<<<dim3(256, 8), 512, 0, stream>>>(qkvb, biasT, attno);
  // proj + scatter-back + gated residual -> x2 (token layout, f32 in d_out)
  gemm_stream_kernel<2, 1><<<128 * 8, 512, 0, stream>>>(
      attno, projwT, proj_b, x2, 65536, 512, 512, 8, x, mod + 1024);
  // MLP: LN+modulate -> xn (bf16)
  ln_kernel<0><<<16384, 256, 0, stream>>>(x2, xn, mod + 1536, mod + 2048);
  gemm_stream_kernel<1, 1><<<128 * 32, 512, 0, stream>>>(
      xn, fc1wT, fc1_b, h1, 65536, 2048, 512, 32, nullptr, nullptr);
  gemm_stream_kernel<3, 4><<<128 * 8, 512, 0, stream>>>(
      h1, fc2wT, fc2_b, out, 65536, 512, 2048, 8, x2, mod + 2560);
}

// Round 14
// 844.457 us; speedup vs baseline: 1.4450x; 1.4450x over previous
//
#include <hip/hip_runtime.h>
#include <hip/hip_bf16.h>
#include <math.h>

// ---------------------------------------------------------------------------
// SwinDiT block, f32 I/O + bf16 MFMA internals, MI355X.
// B=1, D=16,H=64,W=64 -> L=65536 tokens, C=512. Windows 4x8x8=256 tokens,
// 256 windows, 8 heads, d=64. HIDDEN=2048.
// Best verified configuration (Round 10, 846.7 us). Structural GEMM
// experiments (dbuf-64KB, BK32-counted-vmcnt, 256^2-1blk, streaming)
// all regressed vs this 2-barrier 256x128 single-buffer loop.
// ---------------------------------------------------------------------------

typedef __attribute__((ext_vector_type(8))) short short8;   // 8 x bf16
typedef __attribute__((ext_vector_type(4))) short bs4;      // 4 x bf16
typedef __attribute__((ext_vector_type(4))) float f32x4;

typedef const __attribute__((address_space(1))) unsigned int gu32;
typedef __attribute__((address_space(3))) unsigned int lu32;

__device__ __forceinline__ float bf2f(short s) {
  unsigned int u = ((unsigned int)(unsigned short)s) << 16;
  float f;
  __builtin_memcpy(&f, &u, 4);
  return f;
}
__device__ __forceinline__ short f2bf(float f) {
  unsigned int u;
  __builtin_memcpy(&u, &f, 4);
  u += 0x7FFFu + ((u >> 16) & 1u);   // RNE
  return (short)(u >> 16);
}
__device__ __forceinline__ short f2bf_trunc(float f) {
  unsigned int u;
  __builtin_memcpy(&u, &f, 4);
  return (short)(u >> 16);
}

// window-layout row p -> original token index s (roll(-2,-4,-4) + window partition)
__device__ __forceinline__ int win_to_src(int p) {
  int wi = p >> 8, t = p & 255;
  int sd = (((wi >> 6) << 2) + (t >> 6) + 2) & 15;
  int sh = ((((wi >> 3) & 7) << 3) + ((t >> 3) & 7) + 4) & 63;
  int sw = (((wi & 7) << 3) + (t & 7) + 4) & 63;
  return (sd << 12) | (sh << 6) | sw;
}

// ---------------------------------------------------------------------------
// K0: mod = silu(t_emb) @ ada_w + ada_b   -> f32 [3072]
// ---------------------------------------------------------------------------
__global__ __launch_bounds__(256) void mod_kernel(
    const float* __restrict__ t_emb, const float* __restrict__ ada_w,
    const float* __restrict__ ada_b, float* __restrict__ mod) {
  __shared__ float sl[512];
  int tid = threadIdx.x;
  for (int r = 0; r < 2; ++r) {
    float x = t_emb[r * 256 + tid];
    sl[r * 256 + tid] = x / (1.f + expf(-x));
  }
  __syncthreads();
  int col = blockIdx.x * 256 + tid;
  float acc = ada_b[col];
  for (int k = 0; k < 512; ++k)
    acc += sl[k] * ada_w[(size_t)k * 3072 + col];
  mod[col] = acc;
}

// ---------------------------------------------------------------------------
// K1: rel-pos bias expand, TRANSPOSED bf16: biasT[head][key j][q i]
// ---------------------------------------------------------------------------
__global__ __launch_bounds__(256) void bias_kernel(
    const float* __restrict__ rel_table, short* __restrict__ biasT) {
  int head = blockIdx.x >> 8;
  int j = blockIdx.x & 255;   // key
  int i = threadIdx.x;        // q
  int di = i >> 6, hi = (i >> 3) & 7, wi = i & 7;
  int dj = j >> 6, hj = (j >> 3) & 7, wj = j & 7;
  int idx = (di - dj + 3) * 225 + (hi - hj + 7) * 15 + (wi - wj + 7);
  biasT[(size_t)blockIdx.x * 256 + i] = f2bf(rel_table[idx * 8 + head]);
}

// ---------------------------------------------------------------------------
// K2: PERMUTED transpose (all GEMM weights): in f32 [K][Nin] -> out bf16
// [Nin][K], out row j holds logical w column Lcol(j) = (j&~63) + 4*(j&15)
// + ((j>>4)&3).  GEMM frag (n,l15) then maps to 4 CONTIGUOUS logical cols
// -> vectorized epilogue loads/stores.
// grid (Nin/64, K/64), 256 threads.
// ---------------------------------------------------------------------------
__global__ __launch_bounds__(256) void perm_transpose_kernel(
    const float* __restrict__ in, short* __restrict__ out, int Nin, int K) {
  __shared__ float t[64][65];
  int a = blockIdx.x;          // n-block
  int kb = blockIdx.y;         // k-block
  int tx = threadIdx.x & 63, ty = threadIdx.x >> 6;
#pragma unroll
  for (int r = 0; r < 16; ++r) {
    int kk = ty * 16 + r;
    t[kk][tx] = in[(size_t)(kb * 64 + kk) * Nin + a * 64 + tx];
  }
  __syncthreads();
#pragma unroll
  for (int r = 0; r < 16; ++r) {
    int jl = ty * 16 + r;                       // local out row
    int lc = 4 * (jl & 15) + ((jl >> 4) & 3);   // Lcol local
    out[(size_t)(a * 64 + jl) * K + kb * 64 + tx] = f2bf(t[tx][lc]);
  }
}

// ---------------------------------------------------------------------------
// K3: LayerNorm + adaLN modulate. f32 in -> bf16 out.
// GATHER=1: out row p <- src row win_to_src(p)
// ---------------------------------------------------------------------------
template <int GATHER>
__global__ __launch_bounds__(256) void ln_kernel(
    const float* __restrict__ xin, short* __restrict__ xout,
    const float* __restrict__ shv, const float* __restrict__ scv) {
  int wave = threadIdx.x >> 6, lane = threadIdx.x & 63;
  int p = blockIdx.x * 4 + wave;
  int s = GATHER ? win_to_src(p) : p;
  const f32x4* px = (const f32x4*)(xin + (size_t)s * 512 + lane * 8);
  f32x4 a = px[0], b = px[1];
  float xs[8];
#pragma unroll
  for (int j = 0; j < 4; ++j) { xs[j] = a[j]; xs[4 + j] = b[j]; }
  float sum = 0.f, sq = 0.f;
#pragma unroll
  for (int j = 0; j < 8; ++j) { sum += xs[j]; sq += xs[j] * xs[j]; }
#pragma unroll
  for (int off = 1; off < 64; off <<= 1) {
    sum += __shfl_xor(sum, off, 64);
    sq += __shfl_xor(sq, off, 64);
  }
  float mean = sum * (1.f / 512.f);
  float var = sq * (1.f / 512.f) - mean * mean;
  float rs = rsqrtf(var + 1e-5f);
  short8 o;
#pragma unroll
  for (int j = 0; j < 8; ++j) {
    int c = lane * 8 + j;
    float val = (xs[j] - mean) * rs * (1.f + scv[c]) + shv[c];
    o[j] = f2bf(val);
  }
  *(short8*)(xout + (size_t)p * 512 + lane * 8) = o;
}

// ---------------------------------------------------------------------------
// K4: GEMM  C[M,N] = A[M,K](bf16) @ BT[N,K](bf16,row-permuted)^T + bias(f32).
// 256x128 tile, BK=64, 8 waves (512 thr), wave = 64x64 sub-tile (4x4 frags).
// Single-buffer 2-barrier loop, global_load_lds dwordx4 + G4 involution
// swizzle on source+read (proven 0 bank conflicts). LDS 48 KB -> 3 blocks/CU.
// bn-innermost 1-D grid + bijective XCD chunking. All epilogues vectorized
// (lane covers 4 contiguous logical cols colb..colb+3 thanks to permuted BT).
// EPI: 0 = qkv: (acc+bias)*0.125 on q cols -> bs4 store
//      1 = fc1: bias + tanh-GELU -> bs4 store
//      2 = proj: scatter window-row -> token-row; f32x4 resid+gate store
//      3 = fc2:  f32x4 resid+gate store (Cf = d_out)
// ---------------------------------------------------------------------------
template <int EPI>
__global__ __launch_bounds__(512) void gemm_kernel(
    const short* __restrict__ A, const short* __restrict__ BT,
    const float* __restrict__ bias, void* __restrict__ Cv,
    int M, int N, int K, int nbn,
    const float* __restrict__ resid, const float* __restrict__ gate) {
  __shared__ __align__(16) short Atl[256 * 64];   // 32 KB
  __shared__ __align__(16) short Btl[128 * 64];   // 16 KB

  int nwg = gridDim.x;
  int bid = blockIdx.x;
  int q = nwg >> 3, r = nwg & 7;
  int xcd = bid & 7, idx = bid >> 3;
  int swz = (xcd < r ? xcd * (q + 1) : r * (q + 1) + (xcd - r) * q) + idx;
  int bm = swz / nbn, bn = swz % nbn;

  int tid = threadIdx.x;
  int lane = tid & 63, wave = tid >> 6;          // wave 0..7
  int l15 = lane & 15, lg = lane >> 4;
  int wr = (wave >> 1) * 64, wc = (wave & 1) * 64;   // 4x2 wave grid

  const size_t rowb = (size_t)K * 2;
  const char* ga[4];
  const char* gb[2];
  int loA[4], loB[2];
#pragma unroll
  for (int rr = 0; rr < 4; ++rr) {
    int o = rr * 8192 + tid * 16;
    int so = o ^ (((o >> 7) & 7) << 4);     // involution sigma (128-B rows)
    int row = so >> 7, cb = so & 127;
    loA[rr] = o;
    ga[rr] = (const char*)A + (size_t)(bm * 256 + row) * rowb + cb;
  }
#pragma unroll
  for (int rr = 0; rr < 2; ++rr) {
    int o = rr * 8192 + tid * 16;
    int so = o ^ (((o >> 7) & 7) << 4);
    int row = so >> 7, cb = so & 127;
    loB[rr] = o;
    gb[rr] = (const char*)BT + (size_t)(bn * 128 + row) * rowb + cb;
  }

  f32x4 acc[4][4];
#pragma unroll
  for (int m = 0; m < 4; ++m)
#pragma unroll
    for (int n = 0; n < 4; ++n) acc[m][n] = (f32x4){0.f, 0.f, 0.f, 0.f};

  const int swr = (l15 & 7) << 4;

  for (int kt = 0; kt < K; kt += 64) {
#pragma unroll
    for (int rr = 0; rr < 4; ++rr) {
      __builtin_amdgcn_global_load_lds((gu32*)ga[rr], (lu32*)((char*)Atl + loA[rr]), 16, 0, 0);
      ga[rr] += 128;
    }
#pragma unroll
    for (int rr = 0; rr < 2; ++rr) {
      __builtin_amdgcn_global_load_lds((gu32*)gb[rr], (lu32*)((char*)Btl + loB[rr]), 16, 0, 0);
      gb[rr] += 128;
    }
    __syncthreads();

    short8 af[2][4], bfr[2][4];
#pragma unroll
    for (int m = 0; m < 4; ++m) {
      int base = (wr + m * 16 + l15) * 128;
#pragma unroll
      for (int ks = 0; ks < 2; ++ks)
        af[ks][m] = *(const short8*)((const char*)Atl + base + ((ks * 64 + lg * 16) ^ swr));
    }
#pragma unroll
    for (int n = 0; n < 4; ++n) {
      int base = (wc + n * 16 + l15) * 128;
#pragma unroll
      for (int ks = 0; ks < 2; ++ks)
        bfr[ks][n] = *(const short8*)((const char*)Btl + base + ((ks * 64 + lg * 16) ^ swr));
    }
#pragma unroll
    for (int ks = 0; ks < 2; ++ks)
#pragma unroll
      for (int m = 0; m < 4; ++m)
#pragma unroll
        for (int n = 0; n < 4; ++n)
          acc[m][n] = __builtin_amdgcn_mfma_f32_16x16x32_bf16(af[ks][m], bfr[ks][n], acc[m][n], 0, 0, 0);
    __syncthreads();
  }

  // vectorized epilogues: lane covers logical cols colb..colb+3
  int colb = bn * 128 + wc + 4 * l15;
  f32x4 bv4 = *(const f32x4*)(bias + colb);
  if (EPI == 0) {
    float sc = (colb < 512) ? 0.125f : 1.f;   // q-scale (exact pow2)
#pragma unroll
    for (int m = 0; m < 4; ++m)
#pragma unroll
      for (int i = 0; i < 4; ++i) {
        int row = bm * 256 + wr + m * 16 + lg * 4 + i;
        bs4 pk;
#pragma unroll
        for (int n = 0; n < 4; ++n) pk[n] = f2bf_trunc((acc[m][n][i] + bv4[n]) * sc);
        *(bs4*)((short*)Cv + (size_t)row * N + colb) = pk;
      }
  } else if (EPI == 1) {
#pragma unroll
    for (int m = 0; m < 4; ++m)
#pragma unroll
      for (int i = 0; i < 4; ++i) {
        int row = bm * 256 + wr + m * 16 + lg * 4 + i;
        bs4 pk;
#pragma unroll
        for (int n = 0; n < 4; ++n) {
          float v = acc[m][n][i] + bv4[n];
          float tt = v * (0.7978845608f + 0.0356774081f * v * v);
          float sg = 1.f / (1.f + __expf(-2.f * tt));
          pk[n] = f2bf_trunc(v * sg);
        }
        *(bs4*)((short*)Cv + (size_t)row * N + colb) = pk;
      }
  } else {
    f32x4 gv = *(const f32x4*)(gate + colb);
#pragma unroll
    for (int m = 0; m < 4; ++m)
#pragma unroll
      for (int i = 0; i < 4; ++i) {
        int row = bm * 256 + wr + m * 16 + lg * 4 + i;
        int s = (EPI == 2) ? win_to_src(row) : row;
        f32x4 rv = *(const f32x4*)(resid + (size_t)s * 512 + colb);
        f32x4 o;
#pragma unroll
        for (int n = 0; n < 4; ++n) o[n] = rv[n] + gv[n] * (acc[m][n][i] + bv4[n]);
        *(f32x4*)((float*)Cv + (size_t)s * 512 + colb) = o;
      }
  }
}

// ---------------------------------------------------------------------------
// K5: window attention, one block per (window, head), 8 waves x 32 q-rows
// (512 thr). Max-free softmax (bounded logits), per-lane partial sums,
// one deferred reduce. LDS 54272 B -> 2 blocks/CU = 16 waves/CU.
// ---------------------------------------------------------------------------
__global__ __launch_bounds__(512) void attn_kernel(
    const short* __restrict__ qkv, const short* __restrict__ biasT,
    short* __restrict__ aout) {
  __shared__ __align__(16) short vt[64][264];      // V^T: [d][key]   33792 B
  __shared__ __align__(16) short pl[8][32][40];    // per-wave P slice 20480 B
  int win = blockIdx.x, head = blockIdx.y;
  int tid = threadIdx.x, lane = tid & 63, wave = tid >> 6;   // wave 0..7
  int l15 = lane & 15, lg = lane >> 4;
  const short* qp = qkv + (size_t)win * 256 * 1536 + head * 64;
  const short* kp = qp + 512;
  const short* vp = qp + 1024;

  // stage V transposed: 512 threads, thread pair splits d-halves of one key
  int key = tid >> 1, dh = (tid & 1) * 32;
#pragma unroll
  for (int r = 0; r < 4; ++r) {
    short8 vv = *(const short8*)(vp + (size_t)key * 1536 + dh + r * 8);
#pragma unroll
    for (int j = 0; j < 8; ++j) vt[dh + r * 8 + j][key] = vv[j];
  }

  // Q fragments (q pre-scaled by 0.125 in qkv epilogue); wave owns 32 rows
  short8 qf[2][2];
#pragma unroll
  for (int m = 0; m < 2; ++m)
#pragma unroll
    for (int kk = 0; kk < 2; ++kk)
      qf[m][kk] = *(const short8*)(qp + (size_t)(wave * 32 + m * 16 + l15) * 1536 + kk * 32 + lg * 8);

  __syncthreads();

  float lsum[2][4];
  f32x4 ao[2][4];
#pragma unroll
  for (int m = 0; m < 2; ++m)
#pragma unroll
    for (int i = 0; i < 4; ++i) lsum[m][i] = 0.f;
#pragma unroll
  for (int m = 0; m < 2; ++m)
#pragma unroll
    for (int n = 0; n < 4; ++n) ao[m][n] = (f32x4){0.f, 0.f, 0.f, 0.f};

  for (int kc = 0; kc < 4; ++kc) {
    f32x4 sv[2][4];
#pragma unroll
    for (int m = 0; m < 2; ++m)
#pragma unroll
      for (int n = 0; n < 4; ++n) sv[m][n] = (f32x4){0.f, 0.f, 0.f, 0.f};
#pragma unroll
    for (int n = 0; n < 4; ++n)
#pragma unroll
      for (int kk = 0; kk < 2; ++kk) {
        short8 kf = *(const short8*)(kp + (size_t)(kc * 64 + n * 16 + l15) * 1536 + kk * 32 + lg * 8);
#pragma unroll
        for (int m = 0; m < 2; ++m)
          sv[m][n] = __builtin_amdgcn_mfma_f32_16x16x32_bf16(qf[m][kk], kf, sv[m][n], 0, 0, 0);
      }
    // + rel-pos bias, P = exp(S), per-lane partial sums
#pragma unroll
    for (int n = 0; n < 4; ++n) {
      const short* bq = biasT + (size_t)(head * 256 + kc * 64 + n * 16 + l15) * 256 + wave * 32 + lg * 4;
#pragma unroll
      for (int m = 0; m < 2; ++m) {
        bs4 bt = *(const bs4*)(bq + m * 16);
#pragma unroll
        for (int i = 0; i < 4; ++i) {
          float pe = __expf(sv[m][n][i] + bf2f(bt[i]));
          sv[m][n][i] = pe;
          lsum[m][i] += pe;
        }
      }
    }
    // P slices of 32 keys: store -> read A-frag -> PV MFMA
#pragma unroll
    for (int s = 0; s < 2; ++s) {
#pragma unroll
      for (int m = 0; m < 2; ++m)
#pragma unroll
        for (int nn = 0; nn < 2; ++nn) {
          int n = 2 * s + nn;
#pragma unroll
          for (int i = 0; i < 4; ++i)
            pl[wave][m * 16 + lg * 4 + i][nn * 16 + l15] = f2bf_trunc(sv[m][n][i]);
        }
      short8 pf[2];
#pragma unroll
      for (int m = 0; m < 2; ++m)
        pf[m] = *(const short8*)&pl[wave][m * 16 + l15][lg * 8];
#pragma unroll
      for (int n2 = 0; n2 < 4; ++n2) {
        short8 vf = *(const short8*)&vt[n2 * 16 + l15][kc * 64 + s * 32 + lg * 8];
#pragma unroll
        for (int m = 0; m < 2; ++m)
          ao[m][n2] = __builtin_amdgcn_mfma_f32_16x16x32_bf16(pf[m], vf, ao[m][n2], 0, 0, 0);
      }
    }
  }

  // deferred cross-lane sum reduce (within the 16 col-lanes, lg preserved)
#pragma unroll
  for (int m = 0; m < 2; ++m)
#pragma unroll
    for (int i = 0; i < 4; ++i) {
#pragma unroll
      for (int off = 1; off < 16; off <<= 1)
        lsum[m][i] += __shfl_xor(lsum[m][i], off, 64);
    }

  // normalize + store [win-layout token][head*64+d]
#pragma unroll
  for (int m = 0; m < 2; ++m)
#pragma unroll
    for (int i = 0; i < 4; ++i) {
      float inv = 1.f / lsum[m][i];
      int row = win * 256 + wave * 32 + m * 16 + lg * 4 + i;
#pragma unroll
      for (int n = 0; n < 4; ++n)
        aout[(size_t)row * 512 + head * 64 + n * 16 + l15] = f2bf(ao[m][n][i] * inv);
    }
}

// ---------------------------------------------------------------------------
// launch
// ---------------------------------------------------------------------------
extern "C" void kernel_launch(void* const* d_in, const int* in_sizes, int n_in,
                              void* d_out, int out_size, void* d_ws, size_t ws_size,
                              hipStream_t stream) {
  (void)in_sizes; (void)n_in; (void)out_size; (void)ws_size;
  const float* x         = (const float*)d_in[0];
  const float* t_emb     = (const float*)d_in[1];
  const float* ada_w     = (const float*)d_in[2];
  const float* ada_b     = (const float*)d_in[3];
  const float* rel_table = (const float*)d_in[4];
  const float* qkv_w     = (const float*)d_in[5];
  const float* qkv_b     = (const float*)d_in[6];
  const float* proj_w    = (const float*)d_in[7];
  const float* proj_b    = (const float*)d_in[8];
  const float* fc1_w     = (const float*)d_in[9];
  const float* fc1_b     = (const float*)d_in[10];
  const float* fc2_w     = (const float*)d_in[11];
  const float* fc2_b     = (const float*)d_in[12];
  float* out = (float*)d_out;
  char* ws = (char*)d_ws;

  // workspace layout (bytes); total ~327 MB
  float* mod    = (float*)(ws);                    // 3072 f32 (16 KB reserved)
  short* biasT  = (short*)(ws + 16384);            // 8*256*256 bf16 = 1 MB
  short* qkvwT  = (short*)(ws + 16384 + 2097152);  // 1536*512 bf16 (perm)
  short* projwT = qkvwT + 1536 * 512;              // 512*512 (perm)
  short* fc1wT  = projwT + 512 * 512;              // 2048*512 (perm)
  short* fc2wT  = fc1wT + 2048 * 512;              // 512*2048 (perm)
  short* xn     = (short*)(ws + 8404992);          // 65536*512 bf16
  short* qkvb   = xn + (size_t)65536 * 512;        // 65536*1536 bf16
  short* attno  = qkvb + (size_t)65536 * 1536;     // 65536*512 bf16
  short* h1     = qkvb;                            // alias: 65536*2048 over qkvb+attno
  float* x2     = out;                             // MSA residual output lives in d_out

  mod_kernel<<<12, 256, 0, stream>>>(t_emb, ada_w, ada_b, mod);
  bias_kernel<<<2048, 256, 0, stream>>>(rel_table, biasT);
  perm_transpose_kernel<<<dim3(24, 8), 256, 0, stream>>>(qkv_w, qkvwT, 1536, 512);
  perm_transpose_kernel<<<dim3(8, 8), 256, 0, stream>>>(proj_w, projwT, 512, 512);
  perm_transpose_kernel<<<dim3(32, 8), 256, 0, stream>>>(fc1_w, fc1wT, 2048, 512);
  perm_transpose_kernel<<<dim3(8, 32), 256, 0, stream>>>(fc2_w, fc2wT, 512, 2048);

  // MSA: gather+LN+modulate -> xn (window layout, bf16)
  ln_kernel<1><<<16384, 256, 0, stream>>>(x, xn, mod + 0, mod + 512);
  // qkv = xn @ qkv_w + b  (bf16, q pre-scaled); BM=256,BN=128 -> grid 256*12
  gemm_kernel<0><<<256 * 12, 512, 0, stream>>>(xn, qkvwT, qkv_b, qkvb,
                                               65536, 1536, 512, 12, nullptr, nullptr);
  attn_kernel<<<dim3(256, 8), 512, 0, stream>>>(qkvb, biasT, attno);
  // proj + scatter-back + gated residual -> x2 (token layout, f32 in d_out)
  gemm_kernel<2><<<256 * 4, 512, 0, stream>>>(attno, projwT, proj_b, x2,
                                              65536, 512, 512, 4, x, mod + 1024);
  // MLP: LN+modulate -> xn (bf16)
  ln_kernel<0><<<16384, 256, 0, stream>>>(x2, xn, mod + 1536, mod + 2048);
  gemm_kernel<1><<<256 * 16, 512, 0, stream>>>(xn, fc1wT, fc1_b, h1,
                                               65536, 2048, 512, 16, nullptr, nullptr);
  gemm_kernel<3><<<256 * 4, 512, 0, stream>>>(h1, fc2wT, fc2_b, out,
                                              65536, 512, 2048, 4, x2, mod + 2560);
}